// Round 1
// 228.907 us; speedup vs baseline: 1.0428x; 1.0428x over previous
//
#include <hip/hip_runtime.h>
#include <cfloat>

#define C_DIM 256
#define HW    4096
#define NE    1024
#define NPIX  65536
#define TAU   0.15f
#define ZSTR  264   // fp16 per Z-LDS pixel row: 256 ch + 8 pad (528 B, 16B-aligned)

typedef __attribute__((ext_vector_type(8))) _Float16 half8_t;
typedef __attribute__((ext_vector_type(4))) float floatx4;

// monotone float -> uint32 (for packed (d,idx) u64 min with lowest-index tie-break)
__device__ __forceinline__ unsigned int fenc(float f) {
  unsigned int u = __float_as_uint(f);
  return (u & 0x80000000u) ? ~u : (u | 0x80000000u);
}

// ---------------- ws layout (1.05 MB total) ----------------
// @0       float acc (loss)            [zeroed per launch]
// @8       int   ccount                [zeroed per launch]
// @4096    float e2[1024]
// @8192    _Float16 EhfP[1024*256]     (512 KiB fp16 codebook, MFMA-fragment-packed)
// @532480  int   idx[65536]            (256 KiB)
// @794624  int   clist[65536]          (256 KiB, ends 1056768)

// K0a: ||e||^2 per codeword. One wave per codeword.
__global__ __launch_bounds__(256)
void e2_kernel(const float* __restrict__ cb, float* __restrict__ e2) {
  const int wave = (blockIdx.x * 256 + (int)threadIdx.x) >> 6;
  const int lane = threadIdx.x & 63;
  const float4 v = *(const float4*)(cb + (size_t)wave * C_DIM + lane * 4);
  float s = v.x * v.x + v.y * v.y + v.z * v.z + v.w * v.w;
  #pragma unroll
  for (int off = 32; off; off >>= 1) s += __shfl_down(s, off, 64);
  if (lane == 0) e2[wave] = s;
}

// K0b: pack codebook into MFMA A-fragment order.
// EhfP[g][ks][i][lane] (16B each): lane l=(quad<<4|ln) holds cb[g*64+i*16+ln][ks*32+quad*8 .. +8].
__global__ __launch_bounds__(256)
void pack_kernel(const float* __restrict__ cb, _Float16* __restrict__ EhfP) {
  const int g = blockIdx.x >> 3, it = blockIdx.x & 7;
  const int sidx = it * 256 + (int)threadIdx.x;       // (ks*256 + i*64 + lane)
  const int ks = sidx >> 8, i = (sidx >> 6) & 3, lane = sidx & 63;
  const int ln = lane & 15, quad = lane >> 4;
  const float* src = cb + (size_t)(g * 64 + i * 16 + ln) * C_DIM + ks * 32 + quad * 8;
  const float4 v0 = *(const float4*)(src);
  const float4 v1 = *(const float4*)(src + 4);
  half8_t h;
  h[0] = (_Float16)v0.x; h[1] = (_Float16)v0.y; h[2] = (_Float16)v0.z; h[3] = (_Float16)v0.w;
  h[4] = (_Float16)v1.x; h[5] = (_Float16)v1.y; h[6] = (_Float16)v1.z; h[7] = (_Float16)v1.w;
  *(half8_t*)(EhfP + (size_t)g * 16384 + (size_t)sidx * 8) = h;
}

// K1: fp16 MFMA screen. A stream (global/L2) now DEPTH-2 prefetched via 4-slot
// rotation (slot = ks&3; prefetch slot (ks+2)&3) — load-to-use distance = 2 ks-steps
// (~320 cy) >= L2 latency, vs depth-1's ~150 cy which stalled the matrix pipe at ~20%.
// B (LDS, ~120 cy) stays depth-1. Contested pixels -> clist only (no flags/key64;
// rescan overwrites idx directly).
__global__ __launch_bounds__(256, 2)
void screen_kernel(const float* __restrict__ z, const _Float16* __restrict__ EhfP,
                   const float* __restrict__ e2, int* __restrict__ idx_out,
                   int* __restrict__ clist, int* __restrict__ ccount) {
  __shared__ __align__(16) _Float16 Zl[128 * ZSTR];   // 67584 B
  __shared__ float e2l[NE];                           // 4096 B

  const int tid = threadIdx.x;
  const int ptile = blockIdx.x * 128;
  const int b = ptile >> 12, pb = ptile & 4095;
  const float* zb = z + (size_t)b * (C_DIM * HW) + pb;

  // stage Z: z[k][p] fp32 -> Zl[p][k] fp16. Each thread: 8 coalesced scalar loads
  // (one pixel, 8 contiguous channels) -> one ds_write_b128.
  #pragma unroll
  for (int it = 0; it < 16; ++it) {
    const int flat = it * 256 + tid;
    const int p = flat & 127, kb = flat >> 7;
    float f[8];
    #pragma unroll
    for (int j = 0; j < 8; ++j) f[j] = zb[(size_t)(kb * 8 + j) * HW + p];
    half8_t h;
    #pragma unroll
    for (int j = 0; j < 8; ++j) h[j] = (_Float16)f[j];
    *(half8_t*)&Zl[p * ZSTR + kb * 8] = h;
  }
  #pragma unroll
  for (int i = 0; i < 4; ++i) e2l[i * 256 + tid] = e2[i * 256 + tid];
  __syncthreads();

  const int lane = tid & 63;
  const int w = tid >> 6;
  const int wc = w & 1, wp = w >> 1;
  const int ln = lane & 15, quad = lane >> 4;

  // A stream: wave wc's fragments for chunk nc at EhfP + (nc*2+wc)*16384 halves;
  // step (nc,ks), frag i: + ks*2048 + i*512 + lane*8 halves (16B/lane, coalesced).
  const _Float16* aBase = EhfP + (size_t)wc * 16384 + (size_t)lane * 8;
  const char* rowB[4];
  #pragma unroll
  for (int j = 0; j < 4; ++j)
    rowB[j] = (const char*)(&Zl[(wp * 64 + j * 16 + ln) * ZSTR + quad * 8]);

  float d1[4], d2[4]; int i1[4];
  #pragma unroll
  for (int j = 0; j < 4; ++j) { d1[j] = FLT_MAX; d2[j] = FLT_MAX; i1[j] = 0; }

  half8_t abuf[4][4], bbuf[2][4];
  // prologue: A fragments for steps 0 and 1; B fragments for step 0
  #pragma unroll
  for (int i = 0; i < 4; ++i) abuf[0][i] = *(const half8_t*)(aBase + i * 512);
  #pragma unroll
  for (int i = 0; i < 4; ++i) abuf[1][i] = *(const half8_t*)(aBase + 2048 + i * 512);
  #pragma unroll
  for (int j = 0; j < 4; ++j) bbuf[0][j] = *(const half8_t*)(rowB[j]);

  for (int nc = 0; nc < 8; ++nc) {
    floatx4 acc[4][4];
    #pragma unroll
    for (int i = 0; i < 4; ++i)
      #pragma unroll
      for (int j = 0; j < 4; ++j) acc[i][j] = (floatx4){0.f, 0.f, 0.f, 0.f};

    #pragma unroll
    for (int ks = 0; ks < 8; ++ks) {
      const int s = nc * 8 + ks;
      const int ca = ks & 3;            // compute A slot (s&3 == ks&3: nc*8 ≡ 0 mod 4)
      const int pa = (ks + 2) & 3;      // prefetch A slot (step s+2)
      const int cbs = ks & 1;           // compute B slot
      const int pbs = cbs ^ 1;          // prefetch B slot (step s+1)
      // A prefetch: step s+2 (clamped to last step: redundant reload, in-bounds)
      {
        const int sp = s + 2 > 63 ? 63 : s + 2;
        const size_t aoff = (size_t)(sp >> 3) * 32768 + (size_t)(sp & 7) * 2048;
        #pragma unroll
        for (int i = 0; i < 4; ++i) abuf[pa][i] = *(const half8_t*)(aBase + aoff + i * 512);
      }
      // B prefetch: step s+1 (clamped)
      {
        const int s1 = s + 1 > 63 ? 63 : s + 1;
        const int bks = s1 & 7;
        #pragma unroll
        for (int j = 0; j < 4; ++j) bbuf[pbs][j] = *(const half8_t*)(rowB[j] + bks * 64);
      }
      // compute on current buffers
      #pragma unroll
      for (int i = 0; i < 4; ++i)
        #pragma unroll
        for (int j = 0; j < 4; ++j)
          acc[i][j] = __builtin_amdgcn_mfma_f32_16x16x32_f16(abuf[ca][i], bbuf[cbs][j], acc[i][j], 0, 0, 0);
    }

    // epilogue: d' = e2 - 2*dot; per-lane (d1,i1,d2). cw index ascending -> '<' keeps first.
    const int cwb = nc * 128 + wc * 64;
    #pragma unroll
    for (int i = 0; i < 4; ++i) {
      const int cw0 = cwb + i * 16 + quad * 4;    // C/D: row = quad*4 + r (codeword)
      float ee[4];
      #pragma unroll
      for (int r = 0; r < 4; ++r) ee[r] = e2l[cw0 + r];
      #pragma unroll
      for (int j = 0; j < 4; ++j) {
        #pragma unroll
        for (int r = 0; r < 4; ++r) {
          const float d = fmaf(-2.0f, acc[i][j][r], ee[r]);
          const bool lt = d < d1[j];
          const float hi = lt ? d1[j] : d;
          d1[j] = lt ? d : d1[j];
          i1[j] = lt ? (cw0 + r) : i1[j];
          d2[j] = fminf(d2[j], hi);
        }
      }
    }
  }

  // cross-quad butterfly (lanes l, l^16, l^32 share pixel col = lane&15)
  #pragma unroll
  for (int j = 0; j < 4; ++j) {
    #pragma unroll
    for (int m = 16; m <= 32; m <<= 1) {
      const float od1 = __shfl_xor(d1[j], m, 64);
      const int   oi1 = __shfl_xor(i1[j], m, 64);
      const float od2 = __shfl_xor(d2[j], m, 64);
      const bool take = (od1 < d1[j]) || (od1 == d1[j] && oi1 < i1[j]);
      const float hi = take ? d1[j] : od1;
      d1[j] = take ? od1 : d1[j];
      i1[j] = take ? oi1 : i1[j];
      d2[j] = fminf(fminf(d2[j], od2), hi);
    }
  }

  // cross-wave (wc) merge via LDS (reuse Zl)
  __syncthreads();
  float* rd1 = (float*)Zl;
  int*   ri1 = (int*)Zl + 256;
  float* rd2 = (float*)Zl + 512;
  if (lane < 16) {
    #pragma unroll
    for (int j = 0; j < 4; ++j) {
      const int p = wp * 64 + j * 16 + ln;
      rd1[wc * 128 + p] = d1[j];
      ri1[wc * 128 + p] = i1[j];
      rd2[wc * 128 + p] = d2[j];
    }
  }
  __syncthreads();
  if (tid < 128) {
    const float a1 = rd1[tid], b1 = rd1[128 + tid];
    const int   ai = ri1[tid], bi = ri1[128 + tid];
    const float a2 = rd2[tid], b2 = rd2[128 + tid];
    const bool take = (b1 < a1) || (b1 == a1 && bi < ai);
    const float d1f = take ? b1 : a1;
    const int   i1f = take ? bi : ai;
    const float hi  = take ? a1 : b1;
    const float d2f = fminf(fminf(a2, b2), hi);
    const int gp = ptile + tid;
    idx_out[gp] = i1f;
    if ((d2f - d1f) <= TAU) {   // fp16 gap error sigma ~3e-2; TAU = 5 sigma
      const int pos = atomicAdd(ccount, 1);
      clist[pos] = gp;
    }
  }
}

// K2: exact fp32 rescan. One block per group of 4 contested pixels, ALL 1024
// codewords in-block (z staged ONCE per pixel, vs 8x before; no global atomics).
// Thread t: codewords t, 256+t, 512+t, 768+t. fma chain per (cw,px) is
// bit-identical to the previous passing version (k ascending, fmaf, -2*dot+e2).
// Block-local u64-key min (fenc(d)<<32 | cw: lowest-index tie-break) -> direct
// idx overwrite.
__global__ __launch_bounds__(256)
void rescan_kernel(const float* __restrict__ z, const float* __restrict__ cb,
                   const float* __restrict__ e2, const int* __restrict__ clist,
                   const int* __restrict__ ccount, int* __restrict__ idx_out) {
  __shared__ __align__(16) float zl[4][C_DIM];    // [px][k] -> float4 broadcast reads
  __shared__ int pxs[4];
  __shared__ unsigned long long bestk[4];
  const int n = *ccount;
  const int ngroups = (n + 3) >> 2;
  for (int g = blockIdx.x; g < ngroups; g += gridDim.x) {
    const int base = g * 4;
    if ((int)threadIdx.x < 4) {
      pxs[threadIdx.x] = clist[min(base + (int)threadIdx.x, n - 1)];  // pad w/ dup (idempotent)
      bestk[threadIdx.x] = ~0ULL;
    }
    __syncthreads();
    {
      const int k = threadIdx.x;
      #pragma unroll
      for (int i = 0; i < 4; ++i) {
        const int gp = pxs[i];
        zl[i][k] = z[(size_t)(gp >> 12) * (C_DIM * HW) + (size_t)k * HW + (gp & 4095)];
      }
    }
    __syncthreads();
    unsigned long long mykey[4] = {~0ULL, ~0ULL, ~0ULL, ~0ULL};
    #pragma unroll 1
    for (int o = 0; o < 4; ++o) {
      const int cw = o * 256 + (int)threadIdx.x;
      const float* row = cb + (size_t)cw * C_DIM;
      float dot[4] = {0.f, 0.f, 0.f, 0.f};
      #pragma unroll 4
      for (int k0 = 0; k0 < C_DIM; k0 += 4) {
        const float4 ev = *(const float4*)(row + k0);   // coalesced-by-row, L2-hot
        #pragma unroll
        for (int i = 0; i < 4; ++i) {
          const float4 zz = *(const float4*)&zl[i][k0]; // uniform addr -> LDS broadcast
          dot[i] = fmaf(ev.x, zz.x, dot[i]);
          dot[i] = fmaf(ev.y, zz.y, dot[i]);
          dot[i] = fmaf(ev.z, zz.z, dot[i]);
          dot[i] = fmaf(ev.w, zz.w, dot[i]);
        }
      }
      const float ee = e2[cw];
      #pragma unroll
      for (int i = 0; i < 4; ++i) {
        const float d = fmaf(-2.0f, dot[i], ee);
        const unsigned long long key = ((unsigned long long)fenc(d) << 32) | (unsigned)cw;
        mykey[i] = key < mykey[i] ? key : mykey[i];
      }
    }
    // wave-level u64 min reduce, then 1 shared atomic per wave per pixel
    #pragma unroll
    for (int i = 0; i < 4; ++i) {
      unsigned long long k = mykey[i];
      #pragma unroll
      for (int off = 32; off; off >>= 1) {
        const unsigned long long ok = __shfl_xor(k, off, 64);
        k = ok < k ? ok : k;
      }
      if ((threadIdx.x & 63) == 0) atomicMin(&bestk[i], k);
    }
    __syncthreads();
    if ((int)threadIdx.x < 4)
      idx_out[pxs[threadIdx.x]] = (int)(unsigned)(bestk[threadIdx.x] & 0xFFFFFFFFull);
    __syncthreads();
  }
}

// K3: gather zq (NCHW) + loss sum. idx is final (rescan already overwrote contested).
__global__ __launch_bounds__(256)
void gather_loss_kernel(const float* __restrict__ z, const float* __restrict__ cb,
                        const int* __restrict__ idx,
                        float* __restrict__ out, float* __restrict__ acc) {
  const int pg = blockIdx.x * 256 + threadIdx.x;
  const int id = idx[pg];
  const int b = pg >> 12, p = pg & 4095;
  const float* zrow = z   + (size_t)b * (C_DIM * HW) + p;
  float*       orow = out + (size_t)b * (C_DIM * HW) + p;
  const float* erow = cb + (size_t)id * C_DIM;
  float s = 0.f;
  for (int c0 = 0; c0 < C_DIM; c0 += 4) {
    const float4 ev = *(const float4*)(erow + c0);
    const float e[4] = {ev.x, ev.y, ev.z, ev.w};
    #pragma unroll
    for (int j = 0; j < 4; ++j) {
      const float zv = zrow[(size_t)(c0 + j) * HW];
      const float dd = e[j] - zv;
      s = fmaf(dd, dd, s);
      orow[(size_t)(c0 + j) * HW] = e[j];
    }
  }
  __shared__ float sdata[256];
  sdata[threadIdx.x] = s;
  __syncthreads();
  #pragma unroll
  for (int off = 128; off; off >>= 1) {
    if (threadIdx.x < (unsigned)off) sdata[threadIdx.x] += sdata[threadIdx.x + off];
    __syncthreads();
  }
  if (threadIdx.x == 0) atomicAdd(acc, sdata[0]);
}

__global__ void finalize_kernel(const float* __restrict__ acc, float* __restrict__ loss_out) {
  *loss_out = 1.25f * (*acc) * (1.0f / 16777216.0f);
}

extern "C" void kernel_launch(void* const* d_in, const int* in_sizes, int n_in,
                              void* d_out, int out_size, void* d_ws, size_t ws_size,
                              hipStream_t stream) {
  const float* z  = (const float*)d_in[0];
  const float* cb = (const float*)d_in[1];
  float* out = (float*)d_out;
  char* ws = (char*)d_ws;

  float*    acc    = (float*)ws;
  int*      ccount = (int*)(ws + 8);
  float*    e2     = (float*)(ws + 4096);
  _Float16* EhfP   = (_Float16*)(ws + 8192);
  int*      idx    = (int*)(ws + 532480);
  int*      clist  = (int*)(ws + 794624);

  (void)hipMemsetAsync(d_ws, 0, 16, stream);
  e2_kernel<<<NE / 4, 256, 0, stream>>>(cb, e2);
  pack_kernel<<<128, 256, 0, stream>>>(cb, EhfP);
  screen_kernel<<<NPIX / 128, 256, 0, stream>>>(z, EhfP, e2, idx, clist, ccount);
  rescan_kernel<<<1024, 256, 0, stream>>>(z, cb, e2, clist, ccount, idx);
  gather_loss_kernel<<<NPIX / 256, 256, 0, stream>>>(z, cb, idx, out, acc);
  finalize_kernel<<<1, 1, 0, stream>>>(acc, out + 16777216);
}